// Round 4
// baseline (2078.161 us; speedup 1.0000x reference)
//
#include <hip/hip_runtime.h>
#include <cstdint>
#include <cstddef>

#define KKSLOTS 25

// ===========================================================================
// CSR build: counting sort of edges by dst, with precomputed spline records.
// Record (int4): {src, packed_slots(4x5bit), bits(f0), bits(f1)}
// ===========================================================================
__global__ void csr_count_kernel(const int* __restrict__ dst, int* __restrict__ cnt, int E) {
    int e = blockIdx.x * blockDim.x + threadIdx.x;
    if (e < E) atomicAdd(&cnt[dst[e]], 1);
}

#define SCAN_B 256
__global__ __launch_bounds__(SCAN_B) void scan1_kernel(const int* __restrict__ cnt,
                                                       int* __restrict__ off,
                                                       int* __restrict__ bsum, int N) {
    __shared__ int tmp[SCAN_B];
    int g = blockIdx.x * SCAN_B + threadIdx.x;
    int v = (g < N) ? cnt[g] : 0;
    tmp[threadIdx.x] = v;
    __syncthreads();
    for (int d = 1; d < SCAN_B; d <<= 1) {
        int t = (threadIdx.x >= d) ? tmp[threadIdx.x - d] : 0;
        __syncthreads();
        tmp[threadIdx.x] += t;
        __syncthreads();
    }
    if (g < N) off[g] = tmp[threadIdx.x] - v;      // exclusive
    if (threadIdx.x == SCAN_B - 1) bsum[blockIdx.x] = tmp[threadIdx.x];
}

__global__ __launch_bounds__(SCAN_B) void scan2_kernel(int* __restrict__ bsum, int nb) {
    __shared__ int tmp[SCAN_B];
    int v = (threadIdx.x < nb) ? bsum[threadIdx.x] : 0;
    tmp[threadIdx.x] = v;
    __syncthreads();
    for (int d = 1; d < SCAN_B; d <<= 1) {
        int t = (threadIdx.x >= d) ? tmp[threadIdx.x - d] : 0;
        __syncthreads();
        tmp[threadIdx.x] += t;
        __syncthreads();
    }
    if (threadIdx.x < nb) bsum[threadIdx.x] = tmp[threadIdx.x] - v;  // exclusive
}

__global__ void scan3_kernel(int* __restrict__ off, const int* __restrict__ bsum, int N) {
    int g = blockIdx.x * SCAN_B + threadIdx.x;
    if (g < N) off[g] += bsum[blockIdx.x];
}

// fill: off[] is exclusive starts; atomicAdd turns it into "end" offsets.
// After this kernel: off[n] == end(n); start(n) = (n==0) ? 0 : off[n-1].
__global__ void csr_fill_kernel(const int* __restrict__ src, const int* __restrict__ dst,
                                const float* __restrict__ pseudo,
                                int* __restrict__ off, int4* __restrict__ rec, int E) {
    int e = blockIdx.x * blockDim.x + threadIdx.x;
    if (e >= E) return;
    int d = dst[e];
    int p = atomicAdd(&off[d], 1);
    float v0 = pseudo[2 * e + 0] * 4.0f;
    float v1 = pseudo[2 * e + 1] * 4.0f;
    float fl0 = floorf(v0), fl1 = floorf(v1);
    float f0 = v0 - fl0, f1 = v1 - fl1;
    int b0 = (int)fl0, b1 = (int)fl1;
    int i0a = min(max(b0, 0), 4),     i1a = min(max(b1, 0), 4);
    int i0b = min(max(b0 + 1, 0), 4), i1b = min(max(b1 + 1, 0), 4);
    int s00 = i0a * 5 + i1a;   // (1-f0)(1-f1)
    int s01 = i0a * 5 + i1b;   // (1-f0)f1
    int s10 = i0b * 5 + i1a;   // f0(1-f1)
    int s11 = i0b * 5 + i1b;   // f0 f1
    int packed = s00 | (s01 << 5) | (s10 << 10) | (s11 << 15);
    int4 r;
    r.x = src[e];
    r.y = packed;
    r.z = __float_as_int(f0);
    r.w = __float_as_int(f1);
    rec[p] = r;
}

// ===========================================================================
// gather: one wave per node. lane = (edge_par, channel). Accumulate the
// node's [25][I] block in LDS (lane-private columns -> ds_add, no global
// atomics), then stream to acc with float4 stores.
// ===========================================================================
template<int I>
__global__ __launch_bounds__(256) void gather_kernel(
        const float* __restrict__ x, const int4* __restrict__ rec,
        const int* __restrict__ off, float* __restrict__ acc, int nlo, int nhi) {
    constexpr int EPW = 64 / I;
    constexpr int SLOTS = KKSLOTS * I;
    __shared__ float lacc[4][SLOTS];
    int wave = threadIdx.x >> 6;
    int lane = threadIdx.x & 63;
    int n = nlo + blockIdx.x * 4 + wave;
    float* la = lacc[wave];
    #pragma unroll
    for (int t = lane; t < SLOTS; t += 64) la[t] = 0.0f;
    if (n >= nhi) return;
    int endo = off[n];
    int start = (n == 0) ? 0 : off[n - 1];
    int i = lane & (I - 1);
    int ep = lane / I;
    for (int j = start + ep; j < endo; j += EPW) {
        int4 r = rec[j];
        float f0 = __int_as_float(r.z), f1 = __int_as_float(r.w);
        float xv = x[(size_t)r.x * I + i];
        float g0 = 1.0f - f0, g1 = 1.0f - f1;
        int s00 = (r.y) & 31, s01 = (r.y >> 5) & 31, s10 = (r.y >> 10) & 31, s11 = (r.y >> 15) & 31;
        unsafeAtomicAdd(&la[s00 * I + i], g0 * g1 * xv);
        unsafeAtomicAdd(&la[s01 * I + i], g0 * f1 * xv);
        unsafeAtomicAdd(&la[s10 * I + i], f0 * g1 * xv);
        unsafeAtomicAdd(&la[s11 * I + i], f0 * f1 * xv);
    }
    // write out (coalesced float4)
    float4* d4 = (float4*)(acc + (size_t)(n - nlo) * SLOTS);
    const float4* la4 = (const float4*)la;
    #pragma unroll
    for (int t = lane; t < SLOTS / 4; t += 64) d4[t] = la4[t];
}

// ===========================================================================
// dense contraction, register-blocked GEMM:
// hout[n,o] = elu( (sum_k acc[n,k]*W[k,o]) / deg[n] + sum_i hin[n,i]*root[i,o] + bias[o] )
// deg comes from CSR offsets.
// ===========================================================================
template<int I, int O, int TO>
__global__ __launch_bounds__(256) void contract_kernel(
        const float* __restrict__ acc, const float* __restrict__ hin,
        const float* __restrict__ W, const float* __restrict__ root,
        const float* __restrict__ bias, const int* __restrict__ off,
        float* __restrict__ hout, int nlo, int nhi) {
    constexpr int K   = KKSLOTS * I;
    constexpr int KCH = 64;
    constexpr int TN  = 64;
    constexpr int OG  = TO / 4;
    constexpr int NG  = 256 / OG;
    constexpr int NPT = TN / NG;
    __shared__ float a_tile[TN][KCH + 4];
    __shared__ float w_tile[KCH][TO];

    int tid = threadIdx.x;
    int n0 = nlo + blockIdx.x * TN;
    int otile = blockIdx.y * TO;
    int og = tid % OG;
    int ng = tid / OG;
    int obase = otile + og * 4;

    float c[NPT][4];
    #pragma unroll
    for (int j = 0; j < NPT; ++j)
        #pragma unroll
        for (int p = 0; p < 4; ++p) c[j][p] = 0.0f;

    for (int k0 = 0; k0 < K; k0 += KCH) {
        int kk = tid & 63;
        int rbase = (tid >> 6) * (TN / 4);
        int gk = k0 + kk;
        #pragma unroll
        for (int j2 = 0; j2 < TN / 4; ++j2) {
            int nn = rbase + j2;
            int n = n0 + nn;
            float v = 0.0f;
            if (n < nhi && gk < K) v = acc[(size_t)(n - nlo) * K + gk];
            a_tile[nn][kk] = v;
        }
        for (int t = tid; t < KCH * TO; t += 256) {
            int kq = t / TO, oq = t - kq * TO;
            int gkw = k0 + kq;
            int oo = otile + oq;
            w_tile[kq][oq] = (gkw < K && oo < O) ? W[(size_t)gkw * O + oo] : 0.0f;
        }
        __syncthreads();
        #pragma unroll 4
        for (int kk2 = 0; kk2 < KCH; kk2 += 4) {
            float4 wv0 = *(const float4*)&w_tile[kk2 + 0][og * 4];
            float4 wv1 = *(const float4*)&w_tile[kk2 + 1][og * 4];
            float4 wv2 = *(const float4*)&w_tile[kk2 + 2][og * 4];
            float4 wv3 = *(const float4*)&w_tile[kk2 + 3][og * 4];
            #pragma unroll
            for (int j = 0; j < NPT; ++j) {
                float4 av = *(const float4*)&a_tile[ng * NPT + j][kk2];
                c[j][0] = fmaf(av.x, wv0.x, c[j][0]); c[j][1] = fmaf(av.x, wv0.y, c[j][1]);
                c[j][2] = fmaf(av.x, wv0.z, c[j][2]); c[j][3] = fmaf(av.x, wv0.w, c[j][3]);
                c[j][0] = fmaf(av.y, wv1.x, c[j][0]); c[j][1] = fmaf(av.y, wv1.y, c[j][1]);
                c[j][2] = fmaf(av.y, wv1.z, c[j][2]); c[j][3] = fmaf(av.y, wv1.w, c[j][3]);
                c[j][0] = fmaf(av.z, wv2.x, c[j][0]); c[j][1] = fmaf(av.z, wv2.y, c[j][1]);
                c[j][2] = fmaf(av.z, wv2.z, c[j][2]); c[j][3] = fmaf(av.z, wv2.w, c[j][3]);
                c[j][0] = fmaf(av.w, wv3.x, c[j][0]); c[j][1] = fmaf(av.w, wv3.y, c[j][1]);
                c[j][2] = fmaf(av.w, wv3.z, c[j][2]); c[j][3] = fmaf(av.w, wv3.w, c[j][3]);
            }
        }
        __syncthreads();
    }

    if (obase >= O) return;
    bool full4 = (obase + 3 < O);
    #pragma unroll
    for (int j = 0; j < NPT; ++j) {
        int n = n0 + ng * NPT + j;
        if (n >= nhi) continue;
        int endo = off[n];
        int start = (n == 0) ? 0 : off[n - 1];
        float dinv = 1.0f / fmaxf((float)(endo - start), 1.0f);
        float r[4] = {0.0f, 0.0f, 0.0f, 0.0f};
        if (full4) {
            for (int i = 0; i < I; ++i) {
                float hv = hin[(size_t)n * I + i];
                float4 rt = *(const float4*)&root[(size_t)i * O + obase];
                r[0] = fmaf(hv, rt.x, r[0]); r[1] = fmaf(hv, rt.y, r[1]);
                r[2] = fmaf(hv, rt.z, r[2]); r[3] = fmaf(hv, rt.w, r[3]);
            }
        } else {
            for (int i = 0; i < I; ++i) {
                float hv = hin[(size_t)n * I + i];
                #pragma unroll
                for (int p = 0; p < 4; ++p)
                    if (obase + p < O) r[p] = fmaf(hv, root[(size_t)i * O + obase + p], r[p]);
            }
        }
        #pragma unroll
        for (int p = 0; p < 4; ++p) {
            int oo = obase + p;
            if (oo >= O) continue;
            float v = fmaf(c[j][p], dinv, r[p] + bias[oo]);
            hout[(size_t)n * O + oo] = (v > 0.0f) ? v : expm1f(v);
        }
    }
}

// ===========================================================================
// segmented graph sum (batch sorted) + count + head
// ===========================================================================
#define GS_CH 128
__global__ __launch_bounds__(128) void graph_reduce_kernel(
        const float* __restrict__ h3, const int* __restrict__ batch,
        float* __restrict__ g, int N) {
    int o = threadIdx.x;
    if (o >= 124) return;
    int n0 = blockIdx.x * GS_CH;
    int n1 = min(n0 + GS_CH, N);
    float local = 0.0f;
    int cur_b = batch[n0];
    for (int n = n0; n < n1; ++n) {
        int b = batch[n];
        if (b != cur_b) {
            atomicAdd(&g[cur_b * 124 + o], local);
            local = 0.0f;
            cur_b = b;
        }
        local += h3[(size_t)n * 124 + o];
    }
    atomicAdd(&g[cur_b * 124 + o], local);
}

__global__ __launch_bounds__(256) void batch_count_kernel(
        const int* __restrict__ batch, float* __restrict__ cnt, int N) {
    __shared__ int hist[64];
    int tid = threadIdx.x;
    if (tid < 64) hist[tid] = 0;
    __syncthreads();
    int n = blockIdx.x * blockDim.x + tid;
    if (n < N) atomicAdd(&hist[batch[n]], 1);
    __syncthreads();
    if (tid < 64 && hist[tid] > 0) atomicAdd(&cnt[tid], (float)hist[tid]);
}

__global__ void head_kernel(const float* __restrict__ g, const float* __restrict__ cnt,
                            const float* __restrict__ fcw, const float* __restrict__ fcb,
                            float* __restrict__ out) {
    __shared__ float logits[32];
    __shared__ float red[2];
    int b = blockIdx.x;
    int o = threadIdx.x;
    float c = fmaxf(cnt[b], 1.0f);
    if (o < 30) {
        float a = fcb[o];
        for (int i = 0; i < 124; ++i)
            a = fmaf(g[b * 124 + i] / c, fcw[i * 30 + o], a);
        logits[o] = a;
    }
    __syncthreads();
    if (o == 0) {
        float m = -1e30f;
        for (int j = 0; j < 30; ++j) m = fmaxf(m, logits[j]);
        float s = 0.0f;
        for (int j = 0; j < 30; ++j) s += expf(logits[j] - m);
        red[0] = m;
        red[1] = logf(s);
    }
    __syncthreads();
    if (o < 30) out[b * 30 + o] = logits[o] - red[0] - red[1];
}

// ---------------------------------------------------------------------------
// per-layer driver (node-chunked so acc fits whatever ws_size allows)
// ---------------------------------------------------------------------------
template<int I, int O, int TO>
static void run_layer(const float* hin, const float* W, const float* root, const float* bias,
                      float* hout, float* acc, const float* x_unused,
                      const int4* rec, const int* off,
                      int N, int E, size_t avail, hipStream_t stream) {
    size_t perNode = (size_t)KKSLOTS * I * 4;
    size_t maxNodesS = avail / perNode;
    int maxNodes = (maxNodesS > (size_t)N) ? N : (int)maxNodesS;
    if (maxNodes < 4) maxNodes = 4;
    for (int nlo = 0; nlo < N; nlo += maxNodes) {
        int nhi = nlo + maxNodes;
        if (nhi > N) nhi = N;
        int cn = nhi - nlo;
        gather_kernel<I><<<(cn + 3) / 4, 256, 0, stream>>>(hin, rec, off, acc, nlo, nhi);
        dim3 nb((cn + 63) / 64, (O + TO - 1) / TO);
        contract_kernel<I, O, TO><<<nb, 256, 0, stream>>>(acc, hin, W, root, bias, off, hout, nlo, nhi);
    }
}

extern "C" void kernel_launch(void* const* d_in, const int* in_sizes, int n_in,
                              void* d_out, int out_size, void* d_ws, size_t ws_size,
                              hipStream_t stream) {
    const float* x      = (const float*)d_in[0];
    const int*   ei     = (const int*)  d_in[1];
    const float* pseudo = (const float*)d_in[2];
    const int*   batch  = (const int*)  d_in[3];
    const float* W1 = (const float*)d_in[4];
    const float* r1 = (const float*)d_in[5];
    const float* b1 = (const float*)d_in[6];
    const float* W2 = (const float*)d_in[7];
    const float* r2 = (const float*)d_in[8];
    const float* b2 = (const float*)d_in[9];
    const float* W3 = (const float*)d_in[10];
    const float* r3 = (const float*)d_in[11];
    const float* b3 = (const float*)d_in[12];
    const float* fcw = (const float*)d_in[13];
    const float* fcb = (const float*)d_in[14];

    int N = in_sizes[0] / 8;
    int E = in_sizes[1] / 2;
    const int* srcp = ei;
    const int* dstp = ei + E;

    // workspace carve (keep 16B alignment)
    char* p = (char*)d_ws;
    float* h1   = (float*)p; p += (size_t)N * 32 * 4;
    float* h2   = (float*)p; p += (size_t)N * 64 * 4;
    float* h3   = (float*)p; p += (size_t)N * 124 * 4;
    float* gbuf = (float*)p; p += 64 * 124 * 4;
    float* cntF = (float*)p; p += 256;
    int*   cntI = (int*)p;   p += ((size_t)N * 4 + 15) & ~15ULL;
    int*   off  = (int*)p;   p += ((size_t)N * 4 + 15) & ~15ULL;
    int*   bsum = (int*)p;   p += SCAN_B * 4;
    int4*  rec  = (int4*)p;  p += (size_t)E * 16;
    float* acc  = (float*)p;
    size_t used = (size_t)(p - (char*)d_ws);
    size_t avail = (ws_size > used) ? (ws_size - used) : 0;

    // zero: gbuf + cntF + cntI (contiguous)
    hipMemsetAsync(gbuf, 0, 64 * 124 * 4 + 256 + (((size_t)N * 4 + 15) & ~15ULL), stream);

    // CSR build
    int nb_scan = (N + SCAN_B - 1) / SCAN_B;
    csr_count_kernel<<<(E + 255) / 256, 256, 0, stream>>>(dstp, cntI, E);
    scan1_kernel<<<nb_scan, SCAN_B, 0, stream>>>(cntI, off, bsum, N);
    scan2_kernel<<<1, SCAN_B, 0, stream>>>(bsum, nb_scan);
    scan3_kernel<<<nb_scan, SCAN_B, 0, stream>>>(off, bsum, N);
    csr_fill_kernel<<<(E + 255) / 256, 256, 0, stream>>>(srcp, dstp, pseudo, off, rec, E);

    run_layer<8, 32, 32>(x,  W1, r1, b1, h1, acc, x, rec, off, N, E, avail, stream);
    run_layer<32, 64, 64>(h1, W2, r2, b2, h2, acc, x, rec, off, N, E, avail, stream);
    run_layer<64, 124, 64>(h2, W3, r3, b3, h3, acc, x, rec, off, N, E, avail, stream);

    graph_reduce_kernel<<<(N + GS_CH - 1) / GS_CH, 128, 0, stream>>>(h3, batch, gbuf, N);
    batch_count_kernel<<<(N + 255) / 256, 256, 0, stream>>>(batch, cntF, N);
    head_kernel<<<64, 64, 0, stream>>>(gbuf, cntF, fcw, fcb, (float*)d_out);
}

// Round 5
// 2053.760 us; speedup vs baseline: 1.0119x; 1.0119x over previous
//
#include <hip/hip_runtime.h>
#include <cstdint>
#include <cstddef>

#define KKSLOTS 25

// ===========================================================================
// CSR build: counting sort of edges by dst, with precomputed spline records.
// Record (int4): {src, packed_slots(4x5bit), bits(f0), bits(f1)}
// ===========================================================================
__global__ void csr_count_kernel(const int* __restrict__ dst, int* __restrict__ cnt, int E) {
    int e = blockIdx.x * blockDim.x + threadIdx.x;
    if (e < E) atomicAdd(&cnt[dst[e]], 1);
}

#define SCAN_B 256
__global__ __launch_bounds__(SCAN_B) void scan1_kernel(const int* __restrict__ cnt,
                                                       int* __restrict__ off,
                                                       int* __restrict__ bsum, int N) {
    __shared__ int tmp[SCAN_B];
    int g = blockIdx.x * SCAN_B + threadIdx.x;
    int v = (g < N) ? cnt[g] : 0;
    tmp[threadIdx.x] = v;
    __syncthreads();
    for (int d = 1; d < SCAN_B; d <<= 1) {
        int t = (threadIdx.x >= d) ? tmp[threadIdx.x - d] : 0;
        __syncthreads();
        tmp[threadIdx.x] += t;
        __syncthreads();
    }
    if (g < N) off[g] = tmp[threadIdx.x] - v;      // exclusive
    if (threadIdx.x == SCAN_B - 1) bsum[blockIdx.x] = tmp[threadIdx.x];
}

__global__ __launch_bounds__(SCAN_B) void scan2_kernel(int* __restrict__ bsum, int nb) {
    __shared__ int tmp[SCAN_B];
    int v = (threadIdx.x < nb) ? bsum[threadIdx.x] : 0;
    tmp[threadIdx.x] = v;
    __syncthreads();
    for (int d = 1; d < SCAN_B; d <<= 1) {
        int t = (threadIdx.x >= d) ? tmp[threadIdx.x - d] : 0;
        __syncthreads();
        tmp[threadIdx.x] += t;
        __syncthreads();
    }
    if (threadIdx.x < nb) bsum[threadIdx.x] = tmp[threadIdx.x] - v;  // exclusive
}

__global__ void scan3_kernel(int* __restrict__ off, const int* __restrict__ bsum, int N) {
    int g = blockIdx.x * SCAN_B + threadIdx.x;
    if (g < N) off[g] += bsum[blockIdx.x];
}

// fill: off[] is exclusive starts; atomicAdd turns it into "end" offsets.
// After this kernel: off[n] == end(n); start(n) = (n==0) ? 0 : off[n-1].
__global__ void csr_fill_kernel(const int* __restrict__ src, const int* __restrict__ dst,
                                const float* __restrict__ pseudo,
                                int* __restrict__ off, int4* __restrict__ rec, int E) {
    int e = blockIdx.x * blockDim.x + threadIdx.x;
    if (e >= E) return;
    int d = dst[e];
    int p = atomicAdd(&off[d], 1);
    float v0 = pseudo[2 * e + 0] * 4.0f;
    float v1 = pseudo[2 * e + 1] * 4.0f;
    float fl0 = floorf(v0), fl1 = floorf(v1);
    float f0 = v0 - fl0, f1 = v1 - fl1;
    int b0 = (int)fl0, b1 = (int)fl1;
    int i0a = min(max(b0, 0), 4),     i1a = min(max(b1, 0), 4);
    int i0b = min(max(b0 + 1, 0), 4), i1b = min(max(b1 + 1, 0), 4);
    int s00 = i0a * 5 + i1a;   // (1-f0)(1-f1)
    int s01 = i0a * 5 + i1b;   // (1-f0)f1
    int s10 = i0b * 5 + i1a;   // f0(1-f1)
    int s11 = i0b * 5 + i1b;   // f0 f1
    int packed = s00 | (s01 << 5) | (s10 << 10) | (s11 << 15);
    int4 r;
    r.x = src[e];
    r.y = packed;
    r.z = __float_as_int(f0);
    r.w = __float_as_int(f1);
    rec[p] = r;
}

// ===========================================================================
// gather: ONE BLOCK (256 threads) per node. thread = (edge_slot, channel).
// 4-way unrolled edge loop: 4 rec loads then 4 x loads in flight -> MLP.
// Accumulate in block-shared LDS [25][I] via ds_add, stream out float4.
// ===========================================================================
template<int I>
__global__ __launch_bounds__(256) void gather_kernel(
        const float* __restrict__ x, const int4* __restrict__ rec,
        const int* __restrict__ off, float* __restrict__ acc, int nlo) {
    constexpr int SLOTS = KKSLOTS * I;
    constexpr int EPB = 256 / I;       // edge slots per block
    constexpr int U = 4;               // unroll depth
    __shared__ float la[SLOTS];
    int tid = threadIdx.x;
    int n = nlo + blockIdx.x;
    for (int t = tid; t < SLOTS; t += 256) la[t] = 0.0f;
    __syncthreads();
    int endo = off[n];
    int start = (n == 0) ? 0 : off[n - 1];
    int i = tid & (I - 1);
    int ep = tid / I;
    for (int j = start + ep; j < endo; j += U * EPB) {
        int4 r[U];
        float xv[U];
        #pragma unroll
        for (int u = 0; u < U; ++u) {
            int jj = j + u * EPB;
            r[u] = (jj < endo) ? rec[jj] : rec[j];
        }
        #pragma unroll
        for (int u = 0; u < U; ++u)
            xv[u] = x[(size_t)r[u].x * I + i];
        #pragma unroll
        for (int u = 0; u < U; ++u) {
            if (j + u * EPB >= endo) break;
            float f0 = __int_as_float(r[u].z), f1 = __int_as_float(r[u].w);
            float g0 = 1.0f - f0, g1 = 1.0f - f1;
            int pk = r[u].y;
            atomicAdd(&la[((pk      ) & 31) * I + i], g0 * g1 * xv[u]);
            atomicAdd(&la[((pk >> 5 ) & 31) * I + i], g0 * f1 * xv[u]);
            atomicAdd(&la[((pk >> 10) & 31) * I + i], f0 * g1 * xv[u]);
            atomicAdd(&la[((pk >> 15) & 31) * I + i], f0 * f1 * xv[u]);
        }
    }
    __syncthreads();
    float4* d4 = (float4*)(acc + (size_t)(n - nlo) * SLOTS);
    const float4* la4 = (const float4*)la;
    for (int t = tid; t < SLOTS / 4; t += 256) d4[t] = la4[t];
}

// ===========================================================================
// dense contraction, register-blocked GEMM:
// hout[n,o] = elu( (sum_k acc[n,k]*W[k,o]) / deg[n] + sum_i hin[n,i]*root[i,o] + bias[o] )
// deg comes from CSR offsets.
// ===========================================================================
template<int I, int O, int TO>
__global__ __launch_bounds__(256) void contract_kernel(
        const float* __restrict__ acc, const float* __restrict__ hin,
        const float* __restrict__ W, const float* __restrict__ root,
        const float* __restrict__ bias, const int* __restrict__ off,
        float* __restrict__ hout, int nlo, int nhi) {
    constexpr int K   = KKSLOTS * I;
    constexpr int KCH = 64;
    constexpr int TN  = 64;
    constexpr int OG  = TO / 4;
    constexpr int NG  = 256 / OG;
    constexpr int NPT = TN / NG;
    __shared__ float a_tile[TN][KCH + 4];
    __shared__ float w_tile[KCH][TO];

    int tid = threadIdx.x;
    int n0 = nlo + blockIdx.x * TN;
    int otile = blockIdx.y * TO;
    int og = tid % OG;
    int ng = tid / OG;
    int obase = otile + og * 4;

    float c[NPT][4];
    #pragma unroll
    for (int j = 0; j < NPT; ++j)
        #pragma unroll
        for (int p = 0; p < 4; ++p) c[j][p] = 0.0f;

    for (int k0 = 0; k0 < K; k0 += KCH) {
        int kk = tid & 63;
        int rbase = (tid >> 6) * (TN / 4);
        int gk = k0 + kk;
        #pragma unroll
        for (int j2 = 0; j2 < TN / 4; ++j2) {
            int nn = rbase + j2;
            int n = n0 + nn;
            float v = 0.0f;
            if (n < nhi && gk < K) v = acc[(size_t)(n - nlo) * K + gk];
            a_tile[nn][kk] = v;
        }
        for (int t = tid; t < KCH * TO; t += 256) {
            int kq = t / TO, oq = t - kq * TO;
            int gkw = k0 + kq;
            int oo = otile + oq;
            w_tile[kq][oq] = (gkw < K && oo < O) ? W[(size_t)gkw * O + oo] : 0.0f;
        }
        __syncthreads();
        #pragma unroll 4
        for (int kk2 = 0; kk2 < KCH; kk2 += 4) {
            float4 wv0 = *(const float4*)&w_tile[kk2 + 0][og * 4];
            float4 wv1 = *(const float4*)&w_tile[kk2 + 1][og * 4];
            float4 wv2 = *(const float4*)&w_tile[kk2 + 2][og * 4];
            float4 wv3 = *(const float4*)&w_tile[kk2 + 3][og * 4];
            #pragma unroll
            for (int j = 0; j < NPT; ++j) {
                float4 av = *(const float4*)&a_tile[ng * NPT + j][kk2];
                c[j][0] = fmaf(av.x, wv0.x, c[j][0]); c[j][1] = fmaf(av.x, wv0.y, c[j][1]);
                c[j][2] = fmaf(av.x, wv0.z, c[j][2]); c[j][3] = fmaf(av.x, wv0.w, c[j][3]);
                c[j][0] = fmaf(av.y, wv1.x, c[j][0]); c[j][1] = fmaf(av.y, wv1.y, c[j][1]);
                c[j][2] = fmaf(av.y, wv1.z, c[j][2]); c[j][3] = fmaf(av.y, wv1.w, c[j][3]);
                c[j][0] = fmaf(av.z, wv2.x, c[j][0]); c[j][1] = fmaf(av.z, wv2.y, c[j][1]);
                c[j][2] = fmaf(av.z, wv2.z, c[j][2]); c[j][3] = fmaf(av.z, wv2.w, c[j][3]);
                c[j][0] = fmaf(av.w, wv3.x, c[j][0]); c[j][1] = fmaf(av.w, wv3.y, c[j][1]);
                c[j][2] = fmaf(av.w, wv3.z, c[j][2]); c[j][3] = fmaf(av.w, wv3.w, c[j][3]);
            }
        }
        __syncthreads();
    }

    if (obase >= O) return;
    bool full4 = (obase + 3 < O);
    #pragma unroll
    for (int j = 0; j < NPT; ++j) {
        int n = n0 + ng * NPT + j;
        if (n >= nhi) continue;
        int endo = off[n];
        int start = (n == 0) ? 0 : off[n - 1];
        float dinv = 1.0f / fmaxf((float)(endo - start), 1.0f);
        float r[4] = {0.0f, 0.0f, 0.0f, 0.0f};
        if (full4) {
            for (int i = 0; i < I; ++i) {
                float hv = hin[(size_t)n * I + i];
                float4 rt = *(const float4*)&root[(size_t)i * O + obase];
                r[0] = fmaf(hv, rt.x, r[0]); r[1] = fmaf(hv, rt.y, r[1]);
                r[2] = fmaf(hv, rt.z, r[2]); r[3] = fmaf(hv, rt.w, r[3]);
            }
        } else {
            for (int i = 0; i < I; ++i) {
                float hv = hin[(size_t)n * I + i];
                #pragma unroll
                for (int p = 0; p < 4; ++p)
                    if (obase + p < O) r[p] = fmaf(hv, root[(size_t)i * O + obase + p], r[p]);
            }
        }
        #pragma unroll
        for (int p = 0; p < 4; ++p) {
            int oo = obase + p;
            if (oo >= O) continue;
            float v = fmaf(c[j][p], dinv, r[p] + bias[oo]);
            hout[(size_t)n * O + oo] = (v > 0.0f) ? v : expm1f(v);
        }
    }
}

// ===========================================================================
// segmented graph sum (batch sorted) + count + head
// ===========================================================================
#define GS_CH 128
__global__ __launch_bounds__(128) void graph_reduce_kernel(
        const float* __restrict__ h3, const int* __restrict__ batch,
        float* __restrict__ g, int N) {
    int o = threadIdx.x;
    if (o >= 124) return;
    int n0 = blockIdx.x * GS_CH;
    int n1 = min(n0 + GS_CH, N);
    float local = 0.0f;
    int cur_b = batch[n0];
    for (int n = n0; n < n1; ++n) {
        int b = batch[n];
        if (b != cur_b) {
            atomicAdd(&g[cur_b * 124 + o], local);
            local = 0.0f;
            cur_b = b;
        }
        local += h3[(size_t)n * 124 + o];
    }
    atomicAdd(&g[cur_b * 124 + o], local);
}

__global__ __launch_bounds__(256) void batch_count_kernel(
        const int* __restrict__ batch, float* __restrict__ cnt, int N) {
    __shared__ int hist[64];
    int tid = threadIdx.x;
    if (tid < 64) hist[tid] = 0;
    __syncthreads();
    int n = blockIdx.x * blockDim.x + tid;
    if (n < N) atomicAdd(&hist[batch[n]], 1);
    __syncthreads();
    if (tid < 64 && hist[tid] > 0) atomicAdd(&cnt[tid], (float)hist[tid]);
}

__global__ void head_kernel(const float* __restrict__ g, const float* __restrict__ cnt,
                            const float* __restrict__ fcw, const float* __restrict__ fcb,
                            float* __restrict__ out) {
    __shared__ float logits[32];
    __shared__ float red[2];
    int b = blockIdx.x;
    int o = threadIdx.x;
    float c = fmaxf(cnt[b], 1.0f);
    if (o < 30) {
        float a = fcb[o];
        for (int i = 0; i < 124; ++i)
            a = fmaf(g[b * 124 + i] / c, fcw[i * 30 + o], a);
        logits[o] = a;
    }
    __syncthreads();
    if (o == 0) {
        float m = -1e30f;
        for (int j = 0; j < 30; ++j) m = fmaxf(m, logits[j]);
        float s = 0.0f;
        for (int j = 0; j < 30; ++j) s += expf(logits[j] - m);
        red[0] = m;
        red[1] = logf(s);
    }
    __syncthreads();
    if (o < 30) out[b * 30 + o] = logits[o] - red[0] - red[1];
}

// ---------------------------------------------------------------------------
// per-layer driver (node-chunked so acc fits whatever ws_size allows)
// ---------------------------------------------------------------------------
template<int I, int O, int TO>
static void run_layer(const float* hin, const float* W, const float* root, const float* bias,
                      float* hout, float* acc,
                      const int4* rec, const int* off,
                      int N, int E, size_t avail, hipStream_t stream) {
    size_t perNode = (size_t)KKSLOTS * I * 4;
    size_t maxNodesS = avail / perNode;
    int maxNodes = (maxNodesS > (size_t)N) ? N : (int)maxNodesS;
    if (maxNodes < 1) maxNodes = 1;
    for (int nlo = 0; nlo < N; nlo += maxNodes) {
        int nhi = nlo + maxNodes;
        if (nhi > N) nhi = N;
        int cn = nhi - nlo;
        gather_kernel<I><<<cn, 256, 0, stream>>>(hin, rec, off, acc, nlo);
        dim3 nb((cn + 63) / 64, (O + TO - 1) / TO);
        contract_kernel<I, O, TO><<<nb, 256, 0, stream>>>(acc, hin, W, root, bias, off, hout, nlo, nhi);
    }
}

extern "C" void kernel_launch(void* const* d_in, const int* in_sizes, int n_in,
                              void* d_out, int out_size, void* d_ws, size_t ws_size,
                              hipStream_t stream) {
    const float* x      = (const float*)d_in[0];
    const int*   ei     = (const int*)  d_in[1];
    const float* pseudo = (const float*)d_in[2];
    const int*   batch  = (const int*)  d_in[3];
    const float* W1 = (const float*)d_in[4];
    const float* r1 = (const float*)d_in[5];
    const float* b1 = (const float*)d_in[6];
    const float* W2 = (const float*)d_in[7];
    const float* r2 = (const float*)d_in[8];
    const float* b2 = (const float*)d_in[9];
    const float* W3 = (const float*)d_in[10];
    const float* r3 = (const float*)d_in[11];
    const float* b3 = (const float*)d_in[12];
    const float* fcw = (const float*)d_in[13];
    const float* fcb = (const float*)d_in[14];

    int N = in_sizes[0] / 8;
    int E = in_sizes[1] / 2;
    const int* srcp = ei;
    const int* dstp = ei + E;

    // workspace carve (keep 16B alignment)
    char* p = (char*)d_ws;
    float* h1   = (float*)p; p += (size_t)N * 32 * 4;
    float* h2   = (float*)p; p += (size_t)N * 64 * 4;
    float* h3   = (float*)p; p += (size_t)N * 124 * 4;
    float* gbuf = (float*)p; p += 64 * 124 * 4;
    float* cntF = (float*)p; p += 256;
    int*   cntI = (int*)p;   p += ((size_t)N * 4 + 15) & ~15ULL;
    int*   off  = (int*)p;   p += ((size_t)N * 4 + 15) & ~15ULL;
    int*   bsum = (int*)p;   p += SCAN_B * 4;
    int4*  rec  = (int4*)p;  p += (size_t)E * 16;
    float* acc  = (float*)p;
    size_t used = (size_t)(p - (char*)d_ws);
    size_t avail = (ws_size > used) ? (ws_size - used) : 0;

    // zero: gbuf + cntF + cntI (contiguous)
    hipMemsetAsync(gbuf, 0, 64 * 124 * 4 + 256 + (((size_t)N * 4 + 15) & ~15ULL), stream);

    // CSR build
    int nb_scan = (N + SCAN_B - 1) / SCAN_B;
    csr_count_kernel<<<(E + 255) / 256, 256, 0, stream>>>(dstp, cntI, E);
    scan1_kernel<<<nb_scan, SCAN_B, 0, stream>>>(cntI, off, bsum, N);
    scan2_kernel<<<1, SCAN_B, 0, stream>>>(bsum, nb_scan);
    scan3_kernel<<<nb_scan, SCAN_B, 0, stream>>>(off, bsum, N);
    csr_fill_kernel<<<(E + 255) / 256, 256, 0, stream>>>(srcp, dstp, pseudo, off, rec, E);

    run_layer<8, 32, 32>(x,  W1, r1, b1, h1, acc, rec, off, N, E, avail, stream);
    run_layer<32, 64, 64>(h1, W2, r2, b2, h2, acc, rec, off, N, E, avail, stream);
    run_layer<64, 124, 64>(h2, W3, r3, b3, h3, acc, rec, off, N, E, avail, stream);

    graph_reduce_kernel<<<(N + GS_CH - 1) / GS_CH, 128, 0, stream>>>(h3, batch, gbuf, N);
    batch_count_kernel<<<(N + 255) / 256, 256, 0, stream>>>(batch, cntF, N);
    head_kernel<<<64, 64, 0, stream>>>(gbuf, cntF, fcw, fcb, (float*)d_out);
}

// Round 6
// 1008.973 us; speedup vs baseline: 2.0597x; 2.0355x over previous
//
#include <hip/hip_runtime.h>
#include <cstdint>
#include <cstddef>

#define KKSLOTS 25

// ===========================================================================
// CSR build: counting sort of edges by dst, with precomputed spline records.
// Record (int4): {src, packed_slots(4x5bit), bits(f0), bits(f1)}
// ===========================================================================
__global__ void csr_count_kernel(const int* __restrict__ dst, int* __restrict__ cnt, int E) {
    int e = blockIdx.x * blockDim.x + threadIdx.x;
    if (e < E) atomicAdd(&cnt[dst[e]], 1);
}

#define SCAN_B 256
__global__ __launch_bounds__(SCAN_B) void scan1_kernel(const int* __restrict__ cnt,
                                                       int* __restrict__ off,
                                                       int* __restrict__ bsum, int N) {
    __shared__ int tmp[SCAN_B];
    int g = blockIdx.x * SCAN_B + threadIdx.x;
    int v = (g < N) ? cnt[g] : 0;
    tmp[threadIdx.x] = v;
    __syncthreads();
    for (int d = 1; d < SCAN_B; d <<= 1) {
        int t = (threadIdx.x >= d) ? tmp[threadIdx.x - d] : 0;
        __syncthreads();
        tmp[threadIdx.x] += t;
        __syncthreads();
    }
    if (g < N) off[g] = tmp[threadIdx.x] - v;      // exclusive
    if (threadIdx.x == SCAN_B - 1) bsum[blockIdx.x] = tmp[threadIdx.x];
}

__global__ __launch_bounds__(SCAN_B) void scan2_kernel(int* __restrict__ bsum, int nb) {
    __shared__ int tmp[SCAN_B];
    int v = (threadIdx.x < nb) ? bsum[threadIdx.x] : 0;
    tmp[threadIdx.x] = v;
    __syncthreads();
    for (int d = 1; d < SCAN_B; d <<= 1) {
        int t = (threadIdx.x >= d) ? tmp[threadIdx.x - d] : 0;
        __syncthreads();
        tmp[threadIdx.x] += t;
        __syncthreads();
    }
    if (threadIdx.x < nb) bsum[threadIdx.x] = tmp[threadIdx.x] - v;  // exclusive
}

__global__ void scan3_kernel(int* __restrict__ off, const int* __restrict__ bsum, int N) {
    int g = blockIdx.x * SCAN_B + threadIdx.x;
    if (g < N) off[g] += bsum[blockIdx.x];
}

// fill: off[] is exclusive starts; atomicAdd turns it into "end" offsets.
// After this kernel: off[n] == end(n); start(n) = (n==0) ? 0 : off[n-1].
__global__ void csr_fill_kernel(const int* __restrict__ src, const int* __restrict__ dst,
                                const float* __restrict__ pseudo,
                                int* __restrict__ off, int4* __restrict__ rec, int E) {
    int e = blockIdx.x * blockDim.x + threadIdx.x;
    if (e >= E) return;
    int d = dst[e];
    int p = atomicAdd(&off[d], 1);
    float v0 = pseudo[2 * e + 0] * 4.0f;
    float v1 = pseudo[2 * e + 1] * 4.0f;
    float fl0 = floorf(v0), fl1 = floorf(v1);
    float f0 = v0 - fl0, f1 = v1 - fl1;
    int b0 = (int)fl0, b1 = (int)fl1;
    int i0a = min(max(b0, 0), 4),     i1a = min(max(b1, 0), 4);
    int i0b = min(max(b0 + 1, 0), 4), i1b = min(max(b1 + 1, 0), 4);
    int s00 = i0a * 5 + i1a;   // (1-f0)(1-f1)
    int s01 = i0a * 5 + i1b;   // (1-f0)f1
    int s10 = i0b * 5 + i1a;   // f0(1-f1)
    int s11 = i0b * 5 + i1b;   // f0 f1
    int packed = s00 | (s01 << 5) | (s10 << 10) | (s11 << 15);
    int4 r;
    r.x = src[e];
    r.y = packed;
    r.z = __float_as_int(f0);
    r.w = __float_as_int(f1);
    rec[p] = r;
}

// ===========================================================================
// segmented accumulation over dst-sorted edges.
// Each wave owns a contiguous edge range; accumulates into a WAVE-PRIVATE
// LDS tile [25][I] with plain += (lane owns its column; DS ops are in-order,
// so RMW is hazard-safe). Flush per node: plain float4 stores for wholly-
// owned nodes, unsafeAtomicAdd for chunk-boundary nodes (acc pre-zeroed).
// ===========================================================================
template<int I>
__device__ __forceinline__ void edge_add(float* la, int lane, int4 r, const float* __restrict__ x) {
    float f0 = __int_as_float(r.z), f1 = __int_as_float(r.w);
    float g0 = 1.0f - f0, g1 = 1.0f - f1;
    int pk = r.y;
    if constexpr (I == 64) {
        float xv = x[(size_t)r.x * 64 + lane];
        la[((pk      ) & 31) * 64 + lane] += g0 * g1 * xv;
        la[((pk >> 5 ) & 31) * 64 + lane] += g0 * f1 * xv;
        la[((pk >> 10) & 31) * 64 + lane] += f0 * g1 * xv;
        la[((pk >> 15) & 31) * 64 + lane] += f0 * f1 * xv;
    } else if constexpr (I == 32) {
        int ch = lane & 31, half = lane >> 5;
        float xv = x[(size_t)r.x * 32 + ch];
        float wA = half ? f0 : g0;
        int sh = half * 10;
        int sA = (pk >> sh) & 31, sB = (pk >> (sh + 5)) & 31;
        la[sA * 32 + ch] += wA * g1 * xv;
        la[sB * 32 + ch] += wA * f1 * xv;
    } else {  // I == 8, lanes 0..31 active
        int ch = lane & 7, corner = (lane >> 3) & 3;
        bool active = lane < 32;
        float xv = active ? x[(size_t)r.x * 8 + ch] : 0.0f;
        int s = (pk >> (corner * 5)) & 31;
        float w = ((corner & 2) ? f0 : g0) * ((corner & 1) ? f1 : g1);
        if (active) la[s * 8 + ch] += w * xv;
    }
}

template<int I>
__global__ __launch_bounds__(256) void seg_accum_kernel(
        const float* __restrict__ x, const int4* __restrict__ rec,
        const int* __restrict__ off, float* __restrict__ acc,
        int nlo, int nhi) {
    constexpr int SLOTS = KKSLOTS * I;
    __shared__ __align__(16) float la_all[4][SLOTS];
    int wline = threadIdx.x >> 6;
    int lane  = threadIdx.x & 63;
    float* la = la_all[wline];
    int wid = blockIdx.x * 4 + wline;
    int nwt = gridDim.x << 2;

    int e_lo = (nlo == 0) ? 0 : off[nlo - 1];
    int e_hi = off[nhi - 1];
    long long span = (long long)e_hi - e_lo;
    int j0 = e_lo + (int)(span * wid / nwt);
    int j1 = e_lo + (int)(span * (wid + 1) / nwt);

    for (int t = lane; t < SLOTS; t += 64) la[t] = 0.0f;
    if (j0 >= j1) return;

    // smallest n in [nlo, nhi) with off[n] > j0
    int lo = nlo, hi = nhi - 1;
    while (lo < hi) { int mid = (lo + hi) >> 1; if (off[mid] > j0) hi = mid; else lo = mid + 1; }
    int n = lo;
    int j = j0;
    bool left_partial = (((n == 0) ? 0 : off[n - 1]) < j0);

    while (j < j1) {
        int nend = off[n];
        bool right_partial = nend > j1;
        if (right_partial) nend = j1;

        // 4-batched edge processing for MLP
        while (j + 4 <= nend) {
            int4 r0 = rec[j], r1 = rec[j + 1], r2 = rec[j + 2], r3 = rec[j + 3];
            edge_add<I>(la, lane, r0, x);
            edge_add<I>(la, lane, r1, x);
            edge_add<I>(la, lane, r2, x);
            edge_add<I>(la, lane, r3, x);
            j += 4;
        }
        while (j < nend) { edge_add<I>(la, lane, rec[j], x); ++j; }

        // flush node n
        bool partial = left_partial || right_partial;
        float* drow = acc + (size_t)(n - nlo) * SLOTS;
        if (!partial) {
            float4* d4 = (float4*)drow;
            const float4* s4 = (const float4*)la;
            for (int t = lane; t < SLOTS / 4; t += 64) d4[t] = s4[t];
        } else {
            for (int t = lane; t < SLOTS; t += 64) {
                float v = la[t];
                if (v != 0.0f) unsafeAtomicAdd(&drow[t], v);
            }
        }
        for (int t = lane; t < SLOTS; t += 64) la[t] = 0.0f;
        left_partial = false;
        ++n;
    }
}

// ===========================================================================
// dense contraction, register-blocked GEMM:
// hout[n,o] = elu( (sum_k acc[n,k]*W[k,o]) / deg[n] + sum_i hin[n,i]*root[i,o] + bias[o] )
// deg comes from CSR offsets.
// ===========================================================================
template<int I, int O, int TO>
__global__ __launch_bounds__(256) void contract_kernel(
        const float* __restrict__ acc, const float* __restrict__ hin,
        const float* __restrict__ W, const float* __restrict__ root,
        const float* __restrict__ bias, const int* __restrict__ off,
        float* __restrict__ hout, int nlo, int nhi) {
    constexpr int K   = KKSLOTS * I;
    constexpr int KCH = 64;
    constexpr int TN  = 64;
    constexpr int OG  = TO / 4;
    constexpr int NG  = 256 / OG;
    constexpr int NPT = TN / NG;
    __shared__ float a_tile[TN][KCH + 4];
    __shared__ float w_tile[KCH][TO];

    int tid = threadIdx.x;
    int n0 = nlo + blockIdx.x * TN;
    int otile = blockIdx.y * TO;
    int og = tid % OG;
    int ng = tid / OG;
    int obase = otile + og * 4;

    float c[NPT][4];
    #pragma unroll
    for (int j = 0; j < NPT; ++j)
        #pragma unroll
        for (int p = 0; p < 4; ++p) c[j][p] = 0.0f;

    for (int k0 = 0; k0 < K; k0 += KCH) {
        int kk = tid & 63;
        int rbase = (tid >> 6) * (TN / 4);
        int gk = k0 + kk;
        #pragma unroll
        for (int j2 = 0; j2 < TN / 4; ++j2) {
            int nn = rbase + j2;
            int n = n0 + nn;
            float v = 0.0f;
            if (n < nhi && gk < K) v = acc[(size_t)(n - nlo) * K + gk];
            a_tile[nn][kk] = v;
        }
        for (int t = tid; t < KCH * TO; t += 256) {
            int kq = t / TO, oq = t - kq * TO;
            int gkw = k0 + kq;
            int oo = otile + oq;
            w_tile[kq][oq] = (gkw < K && oo < O) ? W[(size_t)gkw * O + oo] : 0.0f;
        }
        __syncthreads();
        #pragma unroll 4
        for (int kk2 = 0; kk2 < KCH; kk2 += 4) {
            float4 wv0 = *(const float4*)&w_tile[kk2 + 0][og * 4];
            float4 wv1 = *(const float4*)&w_tile[kk2 + 1][og * 4];
            float4 wv2 = *(const float4*)&w_tile[kk2 + 2][og * 4];
            float4 wv3 = *(const float4*)&w_tile[kk2 + 3][og * 4];
            #pragma unroll
            for (int j = 0; j < NPT; ++j) {
                float4 av = *(const float4*)&a_tile[ng * NPT + j][kk2];
                c[j][0] = fmaf(av.x, wv0.x, c[j][0]); c[j][1] = fmaf(av.x, wv0.y, c[j][1]);
                c[j][2] = fmaf(av.x, wv0.z, c[j][2]); c[j][3] = fmaf(av.x, wv0.w, c[j][3]);
                c[j][0] = fmaf(av.y, wv1.x, c[j][0]); c[j][1] = fmaf(av.y, wv1.y, c[j][1]);
                c[j][2] = fmaf(av.y, wv1.z, c[j][2]); c[j][3] = fmaf(av.y, wv1.w, c[j][3]);
                c[j][0] = fmaf(av.z, wv2.x, c[j][0]); c[j][1] = fmaf(av.z, wv2.y, c[j][1]);
                c[j][2] = fmaf(av.z, wv2.z, c[j][2]); c[j][3] = fmaf(av.z, wv2.w, c[j][3]);
                c[j][0] = fmaf(av.w, wv3.x, c[j][0]); c[j][1] = fmaf(av.w, wv3.y, c[j][1]);
                c[j][2] = fmaf(av.w, wv3.z, c[j][2]); c[j][3] = fmaf(av.w, wv3.w, c[j][3]);
            }
        }
        __syncthreads();
    }

    if (obase >= O) return;
    bool full4 = (obase + 3 < O);
    #pragma unroll
    for (int j = 0; j < NPT; ++j) {
        int n = n0 + ng * NPT + j;
        if (n >= nhi) continue;
        int endo = off[n];
        int start = (n == 0) ? 0 : off[n - 1];
        float dinv = 1.0f / fmaxf((float)(endo - start), 1.0f);
        float r[4] = {0.0f, 0.0f, 0.0f, 0.0f};
        if (full4) {
            for (int i = 0; i < I; ++i) {
                float hv = hin[(size_t)n * I + i];
                float4 rt = *(const float4*)&root[(size_t)i * O + obase];
                r[0] = fmaf(hv, rt.x, r[0]); r[1] = fmaf(hv, rt.y, r[1]);
                r[2] = fmaf(hv, rt.z, r[2]); r[3] = fmaf(hv, rt.w, r[3]);
            }
        } else {
            for (int i = 0; i < I; ++i) {
                float hv = hin[(size_t)n * I + i];
                #pragma unroll
                for (int p = 0; p < 4; ++p)
                    if (obase + p < O) r[p] = fmaf(hv, root[(size_t)i * O + obase + p], r[p]);
            }
        }
        #pragma unroll
        for (int p = 0; p < 4; ++p) {
            int oo = obase + p;
            if (oo >= O) continue;
            float v = fmaf(c[j][p], dinv, r[p] + bias[oo]);
            hout[(size_t)n * O + oo] = (v > 0.0f) ? v : expm1f(v);
        }
    }
}

// ===========================================================================
// segmented graph sum (batch sorted) + count + head
// ===========================================================================
#define GS_CH 128
__global__ __launch_bounds__(128) void graph_reduce_kernel(
        const float* __restrict__ h3, const int* __restrict__ batch,
        float* __restrict__ g, int N) {
    int o = threadIdx.x;
    if (o >= 124) return;
    int n0 = blockIdx.x * GS_CH;
    int n1 = min(n0 + GS_CH, N);
    float local = 0.0f;
    int cur_b = batch[n0];
    for (int n = n0; n < n1; ++n) {
        int b = batch[n];
        if (b != cur_b) {
            atomicAdd(&g[cur_b * 124 + o], local);
            local = 0.0f;
            cur_b = b;
        }
        local += h3[(size_t)n * 124 + o];
    }
    atomicAdd(&g[cur_b * 124 + o], local);
}

__global__ __launch_bounds__(256) void batch_count_kernel(
        const int* __restrict__ batch, float* __restrict__ cnt, int N) {
    __shared__ int hist[64];
    int tid = threadIdx.x;
    if (tid < 64) hist[tid] = 0;
    __syncthreads();
    int n = blockIdx.x * blockDim.x + tid;
    if (n < N) atomicAdd(&hist[batch[n]], 1);
    __syncthreads();
    if (tid < 64 && hist[tid] > 0) atomicAdd(&cnt[tid], (float)hist[tid]);
}

__global__ void head_kernel(const float* __restrict__ g, const float* __restrict__ cnt,
                            const float* __restrict__ fcw, const float* __restrict__ fcb,
                            float* __restrict__ out) {
    __shared__ float logits[32];
    __shared__ float red[2];
    int b = blockIdx.x;
    int o = threadIdx.x;
    float c = fmaxf(cnt[b], 1.0f);
    if (o < 30) {
        float a = fcb[o];
        for (int i = 0; i < 124; ++i)
            a = fmaf(g[b * 124 + i] / c, fcw[i * 30 + o], a);
        logits[o] = a;
    }
    __syncthreads();
    if (o == 0) {
        float m = -1e30f;
        for (int j = 0; j < 30; ++j) m = fmaxf(m, logits[j]);
        float s = 0.0f;
        for (int j = 0; j < 30; ++j) s += expf(logits[j] - m);
        red[0] = m;
        red[1] = logf(s);
    }
    __syncthreads();
    if (o < 30) out[b * 30 + o] = logits[o] - red[0] - red[1];
}

// ---------------------------------------------------------------------------
// per-layer driver (node-chunked so acc fits whatever ws_size allows)
// ---------------------------------------------------------------------------
template<int I, int O, int TO>
static void run_layer(const float* hin, const float* W, const float* root, const float* bias,
                      float* hout, float* acc,
                      const int4* rec, const int* off,
                      int N, int E, size_t avail, hipStream_t stream) {
    size_t perNode = (size_t)KKSLOTS * I * 4;
    size_t maxNodesS = avail / perNode;
    int maxNodes = (maxNodesS > (size_t)N) ? N : (int)maxNodesS;
    if (maxNodes < 1) maxNodes = 1;
    for (int nlo = 0; nlo < N; nlo += maxNodes) {
        int nhi = nlo + maxNodes;
        if (nhi > N) nhi = N;
        int cn = nhi - nlo;
        hipMemsetAsync(acc, 0, (size_t)cn * perNode, stream);
        seg_accum_kernel<I><<<1024, 256, 0, stream>>>(hin, rec, off, acc, nlo, nhi);
        dim3 nb((cn + 63) / 64, (O + TO - 1) / TO);
        contract_kernel<I, O, TO><<<nb, 256, 0, stream>>>(acc, hin, W, root, bias, off, hout, nlo, nhi);
    }
}

extern "C" void kernel_launch(void* const* d_in, const int* in_sizes, int n_in,
                              void* d_out, int out_size, void* d_ws, size_t ws_size,
                              hipStream_t stream) {
    const float* x      = (const float*)d_in[0];
    const int*   ei     = (const int*)  d_in[1];
    const float* pseudo = (const float*)d_in[2];
    const int*   batch  = (const int*)  d_in[3];
    const float* W1 = (const float*)d_in[4];
    const float* r1 = (const float*)d_in[5];
    const float* b1 = (const float*)d_in[6];
    const float* W2 = (const float*)d_in[7];
    const float* r2 = (const float*)d_in[8];
    const float* b2 = (const float*)d_in[9];
    const float* W3 = (const float*)d_in[10];
    const float* r3 = (const float*)d_in[11];
    const float* b3 = (const float*)d_in[12];
    const float* fcw = (const float*)d_in[13];
    const float* fcb = (const float*)d_in[14];

    int N = in_sizes[0] / 8;
    int E = in_sizes[1] / 2;
    const int* srcp = ei;
    const int* dstp = ei + E;

    // workspace carve (keep 16B alignment)
    char* p = (char*)d_ws;
    float* h1   = (float*)p; p += (size_t)N * 32 * 4;
    float* h2   = (float*)p; p += (size_t)N * 64 * 4;
    float* h3   = (float*)p; p += (size_t)N * 124 * 4;
    float* gbuf = (float*)p; p += 64 * 124 * 4;
    float* cntF = (float*)p; p += 256;
    int*   cntI = (int*)p;   p += ((size_t)N * 4 + 15) & ~15ULL;
    int*   off  = (int*)p;   p += ((size_t)N * 4 + 15) & ~15ULL;
    int*   bsum = (int*)p;   p += SCAN_B * 4;
    int4*  rec  = (int4*)p;  p += (size_t)E * 16;
    float* acc  = (float*)p;
    size_t used = (size_t)(p - (char*)d_ws);
    size_t avail = (ws_size > used) ? (ws_size - used) : 0;

    // zero: gbuf + cntF + cntI (contiguous)
    hipMemsetAsync(gbuf, 0, 64 * 124 * 4 + 256 + (((size_t)N * 4 + 15) & ~15ULL), stream);

    // CSR build
    int nb_scan = (N + SCAN_B - 1) / SCAN_B;
    csr_count_kernel<<<(E + 255) / 256, 256, 0, stream>>>(dstp, cntI, E);
    scan1_kernel<<<nb_scan, SCAN_B, 0, stream>>>(cntI, off, bsum, N);
    scan2_kernel<<<1, SCAN_B, 0, stream>>>(bsum, nb_scan);
    scan3_kernel<<<nb_scan, SCAN_B, 0, stream>>>(off, bsum, N);
    csr_fill_kernel<<<(E + 255) / 256, 256, 0, stream>>>(srcp, dstp, pseudo, off, rec, E);

    run_layer<8, 32, 32>(x,  W1, r1, b1, h1, acc, rec, off, N, E, avail, stream);
    run_layer<32, 64, 64>(h1, W2, r2, b2, h2, acc, rec, off, N, E, avail, stream);
    run_layer<64, 124, 64>(h2, W3, r3, b3, h3, acc, rec, off, N, E, avail, stream);

    graph_reduce_kernel<<<(N + GS_CH - 1) / GS_CH, 128, 0, stream>>>(h3, batch, gbuf, N);
    batch_count_kernel<<<(N + 255) / 256, 256, 0, stream>>>(batch, cntF, N);
    head_kernel<<<64, 64, 0, stream>>>(gbuf, cntF, fcw, fcb, (float*)d_out);
}

// Round 7
// 506.772 us; speedup vs baseline: 4.1008x; 1.9910x over previous
//
#include <hip/hip_runtime.h>
#include <cstdint>
#include <cstddef>

#define KKSLOTS 25

typedef __attribute__((ext_vector_type(8))) short short8;
typedef __attribute__((ext_vector_type(4))) float f32x4;
typedef __attribute__((ext_vector_type(4))) unsigned short us4;

__device__ __forceinline__ unsigned short f2bf(float f) {
    unsigned u = __float_as_uint(f);
    u += 0x7FFF + ((u >> 16) & 1);           // RNE
    return (unsigned short)(u >> 16);
}
__device__ __forceinline__ float bf2f(unsigned short b) {
    return __uint_as_float((unsigned)b << 16);
}

// ===========================================================================
// CSR build: counting sort of edges by dst, with precomputed spline records.
// Record (int4): {src, packed_slots(4x5bit), bits(f0), bits(f1)}
// ===========================================================================
__global__ void csr_count_kernel(const int* __restrict__ dst, int* __restrict__ cnt, int E) {
    int e = blockIdx.x * blockDim.x + threadIdx.x;
    if (e < E) atomicAdd(&cnt[dst[e]], 1);
}

#define SCAN_B 256
__global__ __launch_bounds__(SCAN_B) void scan1_kernel(const int* __restrict__ cnt,
                                                       int* __restrict__ off,
                                                       int* __restrict__ bsum, int N) {
    __shared__ int tmp[SCAN_B];
    int g = blockIdx.x * SCAN_B + threadIdx.x;
    int v = (g < N) ? cnt[g] : 0;
    tmp[threadIdx.x] = v;
    __syncthreads();
    for (int d = 1; d < SCAN_B; d <<= 1) {
        int t = (threadIdx.x >= d) ? tmp[threadIdx.x - d] : 0;
        __syncthreads();
        tmp[threadIdx.x] += t;
        __syncthreads();
    }
    if (g < N) off[g] = tmp[threadIdx.x] - v;      // exclusive
    if (threadIdx.x == SCAN_B - 1) bsum[blockIdx.x] = tmp[threadIdx.x];
}

__global__ __launch_bounds__(SCAN_B) void scan2_kernel(int* __restrict__ bsum, int nb) {
    __shared__ int tmp[SCAN_B];
    int v = (threadIdx.x < nb) ? bsum[threadIdx.x] : 0;
    tmp[threadIdx.x] = v;
    __syncthreads();
    for (int d = 1; d < SCAN_B; d <<= 1) {
        int t = (threadIdx.x >= d) ? tmp[threadIdx.x - d] : 0;
        __syncthreads();
        tmp[threadIdx.x] += t;
        __syncthreads();
    }
    if (threadIdx.x < nb) bsum[threadIdx.x] = tmp[threadIdx.x] - v;  // exclusive
}

__global__ void scan3_kernel(int* __restrict__ off, const int* __restrict__ bsum, int N) {
    int g = blockIdx.x * SCAN_B + threadIdx.x;
    if (g < N) off[g] += bsum[blockIdx.x];
}

// After this kernel: off[n] == end(n); start(n) = (n==0) ? 0 : off[n-1].
__global__ void csr_fill_kernel(const int* __restrict__ src, const int* __restrict__ dst,
                                const float* __restrict__ pseudo,
                                int* __restrict__ off, int4* __restrict__ rec, int E) {
    int e = blockIdx.x * blockDim.x + threadIdx.x;
    if (e >= E) return;
    int d = dst[e];
    int p = atomicAdd(&off[d], 1);
    float v0 = pseudo[2 * e + 0] * 4.0f;
    float v1 = pseudo[2 * e + 1] * 4.0f;
    float fl0 = floorf(v0), fl1 = floorf(v1);
    float f0 = v0 - fl0, f1 = v1 - fl1;
    int b0 = (int)fl0, b1 = (int)fl1;
    int i0a = min(max(b0, 0), 4),     i1a = min(max(b1, 0), 4);
    int i0b = min(max(b0 + 1, 0), 4), i1b = min(max(b1 + 1, 0), 4);
    int s00 = i0a * 5 + i1a;
    int s01 = i0a * 5 + i1b;
    int s10 = i0b * 5 + i1a;
    int s11 = i0b * 5 + i1b;
    int packed = s00 | (s01 << 5) | (s10 << 10) | (s11 << 15);
    int4 r;
    r.x = src[e];
    r.y = packed;
    r.z = __float_as_int(f0);
    r.w = __float_as_int(f1);
    rec[p] = r;
}

// ===========================================================================
// fp32 -> bf16 elementwise
// ===========================================================================
__global__ void to_bf16_kernel(const float* __restrict__ in, unsigned short* __restrict__ out, int n) {
    int i = blockIdx.x * 256 + threadIdx.x;
    if (i < n) out[i] = f2bf(in[i]);
}

// ===========================================================================
// build WT[OP][KP] bf16 = transpose of [W ; root] padded with zeros.
// ===========================================================================
template<int KP, int I, int O, int OP>
__global__ void build_wt_kernel(const float* __restrict__ W, const float* __restrict__ root,
                                unsigned short* __restrict__ WT) {
    int idx = blockIdx.x * 256 + threadIdx.x;
    if (idx >= OP * KP) return;
    int o = idx / KP, k = idx - o * KP;
    float v = 0.0f;
    if (o < O) {
        if (k < KKSLOTS * I) v = W[(size_t)k * O + o];
        else if (k < (KKSLOTS + 1) * I) v = root[(size_t)(k - KKSLOTS * I) * O + o];
    }
    WT[idx] = f2bf(v);
}

// ===========================================================================
// segmented accumulation over dst-sorted edges, NODE-ALIGNED wave ranges.
// Wave-private LDS tile [25][I] fp32, plain += (lane owns its column).
// Flush per node: row = [ bf16(la * 1/deg) | hin(bf16) | zeros ] of length KP.
// No atomics, no memset: every node in [nlo,nhi) is flushed by its owner.
// ===========================================================================
template<int I>
__device__ __forceinline__ void edge_add(float* la, int lane, int4 r,
                                         const unsigned short* __restrict__ xb) {
    float f0 = __int_as_float(r.z), f1 = __int_as_float(r.w);
    float g0 = 1.0f - f0, g1 = 1.0f - f1;
    int pk = r.y;
    if constexpr (I == 64) {
        float xv = bf2f(xb[(size_t)r.x * 64 + lane]);
        la[((pk      ) & 31) * 64 + lane] += g0 * g1 * xv;
        la[((pk >> 5 ) & 31) * 64 + lane] += g0 * f1 * xv;
        la[((pk >> 10) & 31) * 64 + lane] += f0 * g1 * xv;
        la[((pk >> 15) & 31) * 64 + lane] += f0 * f1 * xv;
    } else if constexpr (I == 32) {
        int ch = lane & 31, half = lane >> 5;
        float xv = bf2f(xb[(size_t)r.x * 32 + ch]);
        float wA = half ? f0 : g0;
        int sh = half * 10;
        int sA = (pk >> sh) & 31, sB = (pk >> (sh + 5)) & 31;
        la[sA * 32 + ch] += wA * g1 * xv;
        la[sB * 32 + ch] += wA * f1 * xv;
    } else {  // I == 8, lanes 0..31 active
        int ch = lane & 7, corner = (lane >> 3) & 3;
        if (lane < 32) {
            float xv = bf2f(xb[(size_t)r.x * 8 + ch]);
            int s = (pk >> (corner * 5)) & 31;
            float w = ((corner & 2) ? f0 : g0) * ((corner & 1) ? f1 : g1);
            la[s * 8 + ch] += w * xv;
        }
    }
}

template<int I, int KP>
__global__ __launch_bounds__(256) void seg_accum_kernel(
        const unsigned short* __restrict__ xb, const int4* __restrict__ rec,
        const int* __restrict__ off, unsigned short* __restrict__ accB,
        int nlo, int nhi) {
    constexpr int SLOTS = KKSLOTS * I;
    __shared__ float la_all[4][SLOTS];
    int wline = threadIdx.x >> 6, lane = threadIdx.x & 63;
    float* la = la_all[wline];
    int wid = blockIdx.x * 4 + wline;
    int nwt = gridDim.x << 2;

    int e_lo = (nlo == 0) ? 0 : off[nlo - 1];
    int e_hi = off[nhi - 1];
    long long span = (long long)e_hi - e_lo;
    int t0 = e_lo + (int)(span * wid / nwt);
    int t1 = e_lo + (int)(span * (wid + 1) / nwt);

    int ns, ne;
    {   int lo = nlo, hi = nhi;
        while (lo < hi) { int m = (lo + hi) >> 1; if (off[m] > t0) hi = m; else lo = m + 1; }
        ns = (wid == 0) ? nlo : lo; }
    {   int lo = nlo, hi = nhi;
        while (lo < hi) { int m = (lo + hi) >> 1; if (off[m] > t1) hi = m; else lo = m + 1; }
        ne = (wid == nwt - 1) ? nhi : lo; }
    if (ns >= ne) return;

    for (int t = lane; t < SLOTS; t += 64) la[t] = 0.0f;
    int j = (ns == 0) ? 0 : off[ns - 1];
    for (int n = ns; n < ne; ++n) {
        int je = off[n];
        int jstart = j;
        while (j + 4 <= je) {
            int4 r0 = rec[j], r1 = rec[j + 1], r2 = rec[j + 2], r3 = rec[j + 3];
            edge_add<I>(la, lane, r0, xb);
            edge_add<I>(la, lane, r1, xb);
            edge_add<I>(la, lane, r2, xb);
            edge_add<I>(la, lane, r3, xb);
            j += 4;
        }
        while (j < je) { edge_add<I>(la, lane, rec[j], xb); ++j; }

        // flush node n
        float dinv = 1.0f / fmaxf((float)(je - jstart), 1.0f);
        unsigned short* drow = accB + (size_t)(n - nlo) * KP;
        for (int t = lane; t < SLOTS; t += 64) drow[t] = f2bf(la[t] * dinv);
        for (int t = SLOTS + lane; t < KP; t += 64) {
            int ii = t - SLOTS;
            drow[t] = (ii < I) ? xb[(size_t)n * I + ii] : (unsigned short)0;
        }
        for (int t = lane; t < SLOTS; t += 64) la[t] = 0.0f;
    }
}

// ===========================================================================
// MFMA contraction: hout[n][o] = ELU( accB[n][:] . WT[o][:] + bias[o] )
// accB rows already hold [acc/deg | hin], WT rows hold [W ; root]^T.
// Block: 256 threads = 4 waves; wave = 16 nodes; per k-step of 32:
//   A-frag from global (lane: node=l16, k=quad*8+j), B-frags from LDS WT tile.
// mfma_f32_16x16x32_bf16; C/D: col=lane&15, row=quad*4+reg.
// ===========================================================================
template<int KP, int O, int OP>
__global__ __launch_bounds__(256) void contract_mfma_kernel(
        const unsigned short* __restrict__ accB, const unsigned short* __restrict__ WT,
        const float* __restrict__ bias, unsigned short* __restrict__ hout,
        int nlo, int nhi) {
    constexpr int NF = OP / 16;
    constexpr int LDW = 40;                    // padded LDS row stride (bf16 units)
    __shared__ unsigned short wTl[OP][LDW];
    int tid = threadIdx.x;
    int wv = tid >> 6, lane = tid & 63;
    int quad = lane >> 4, l16 = lane & 15;
    int n0 = nlo + blockIdx.x * 64;

    int an = n0 + wv * 16 + l16;               // node for A-operand
    int arow = min(an, nhi - 1) - nlo;

    f32x4 acc[NF];
    #pragma unroll
    for (int t = 0; t < NF; ++t) acc[t] = (f32x4){0.0f, 0.0f, 0.0f, 0.0f};

    for (int k0 = 0; k0 < KP; k0 += 32) {
        // stage WT tile [OP][32] into LDS (8B per thread-slot)
        for (int t = tid; t < OP * 8; t += 256) {
            int o = t >> 3;
            int kk = (t & 7) * 4;
            *(us4*)&wTl[o][kk] = *(const us4*)&WT[(size_t)o * KP + k0 + kk];
        }
        __syncthreads();
        short8 a = *(const short8*)(accB + (size_t)arow * KP + k0 + quad * 8);
        #pragma unroll
        for (int t = 0; t < NF; ++t) {
            short8 b = *(const short8*)&wTl[t * 16 + l16][quad * 8];
            acc[t] = __builtin_amdgcn_mfma_f32_16x16x32_bf16(a, b, acc[t], 0, 0, 0);
        }
        __syncthreads();
    }

    // epilogue: bias + ELU, store bf16
    #pragma unroll
    for (int t = 0; t < NF; ++t) {
        int o = t * 16 + l16;
        if (o >= O) continue;
        float bs = bias[o];
        #pragma unroll
        for (int r = 0; r < 4; ++r) {
            int n = n0 + wv * 16 + quad * 4 + r;
            if (n >= nhi) continue;
            float v = acc[t][r] + bs;
            v = (v > 0.0f) ? v : expm1f(v);
            hout[(size_t)n * O + o] = f2bf(v);
        }
    }
}

// ===========================================================================
// segmented graph sum (batch sorted, h3 bf16) + count + head
// ===========================================================================
#define GS_CH 128
__global__ __launch_bounds__(128) void graph_reduce_kernel(
        const unsigned short* __restrict__ h3, const int* __restrict__ batch,
        float* __restrict__ g, int N) {
    int o = threadIdx.x;
    if (o >= 124) return;
    int n0 = blockIdx.x * GS_CH;
    int n1 = min(n0 + GS_CH, N);
    float local = 0.0f;
    int cur_b = batch[n0];
    for (int n = n0; n < n1; ++n) {
        int b = batch[n];
        if (b != cur_b) {
            atomicAdd(&g[cur_b * 124 + o], local);
            local = 0.0f;
            cur_b = b;
        }
        local += bf2f(h3[(size_t)n * 124 + o]);
    }
    atomicAdd(&g[cur_b * 124 + o], local);
}

__global__ __launch_bounds__(256) void batch_count_kernel(
        const int* __restrict__ batch, float* __restrict__ cnt, int N) {
    __shared__ int hist[64];
    int tid = threadIdx.x;
    if (tid < 64) hist[tid] = 0;
    __syncthreads();
    int n = blockIdx.x * blockDim.x + tid;
    if (n < N) atomicAdd(&hist[batch[n]], 1);
    __syncthreads();
    if (tid < 64 && hist[tid] > 0) atomicAdd(&cnt[tid], (float)hist[tid]);
}

__global__ void head_kernel(const float* __restrict__ g, const float* __restrict__ cnt,
                            const float* __restrict__ fcw, const float* __restrict__ fcb,
                            float* __restrict__ out) {
    __shared__ float logits[32];
    __shared__ float red[2];
    int b = blockIdx.x;
    int o = threadIdx.x;
    float c = fmaxf(cnt[b], 1.0f);
    if (o < 30) {
        float a = fcb[o];
        for (int i = 0; i < 124; ++i)
            a = fmaf(g[b * 124 + i] / c, fcw[i * 30 + o], a);
        logits[o] = a;
    }
    __syncthreads();
    if (o == 0) {
        float m = -1e30f;
        for (int j = 0; j < 30; ++j) m = fmaxf(m, logits[j]);
        float s = 0.0f;
        for (int j = 0; j < 30; ++j) s += expf(logits[j] - m);
        red[0] = m;
        red[1] = logf(s);
    }
    __syncthreads();
    if (o < 30) out[b * 30 + o] = logits[o] - red[0] - red[1];
}

// ---------------------------------------------------------------------------
// per-layer driver (node-chunked so acc fits whatever ws_size allows)
// ---------------------------------------------------------------------------
template<int I, int O, int OP>
static void run_layer(const unsigned short* hb, const unsigned short* WT, const float* bias,
                      unsigned short* hout, unsigned short* accB,
                      const int4* rec, const int* off,
                      int N, size_t avail, hipStream_t stream) {
    constexpr int KP = ((26 * I + 31) / 32) * 32;
    size_t perNode = (size_t)KP * 2;
    size_t maxNodesS = avail / perNode;
    int maxNodes = (maxNodesS > (size_t)N) ? N : (int)maxNodesS;
    if (maxNodes < 64) maxNodes = 64;
    for (int nlo = 0; nlo < N; nlo += maxNodes) {
        int nhi = nlo + maxNodes;
        if (nhi > N) nhi = N;
        int cn = nhi - nlo;
        seg_accum_kernel<I, KP><<<1024, 256, 0, stream>>>(hb, rec, off, accB, nlo, nhi);
        contract_mfma_kernel<KP, O, OP><<<(cn + 63) / 64, 256, 0, stream>>>(
            accB, WT, bias, hout, nlo, nhi);
    }
}

extern "C" void kernel_launch(void* const* d_in, const int* in_sizes, int n_in,
                              void* d_out, int out_size, void* d_ws, size_t ws_size,
                              hipStream_t stream) {
    const float* x      = (const float*)d_in[0];
    const int*   ei     = (const int*)  d_in[1];
    const float* pseudo = (const float*)d_in[2];
    const int*   batch  = (const int*)  d_in[3];
    const float* W1 = (const float*)d_in[4];
    const float* r1 = (const float*)d_in[5];
    const float* b1 = (const float*)d_in[6];
    const float* W2 = (const float*)d_in[7];
    const float* r2 = (const float*)d_in[8];
    const float* b2 = (const float*)d_in[9];
    const float* W3 = (const float*)d_in[10];
    const float* r3 = (const float*)d_in[11];
    const float* b3 = (const float*)d_in[12];
    const float* fcw = (const float*)d_in[13];
    const float* fcb = (const float*)d_in[14];

    int N = in_sizes[0] / 8;
    int E = in_sizes[1] / 2;
    const int* srcp = ei;
    const int* dstp = ei + E;

    constexpr int KP1 = 224, KP2 = 832, KP3 = 1664;

    // workspace carve (all pieces 16B-multiple)
    char* p = (char*)d_ws;
    unsigned short* xb  = (unsigned short*)p; p += (size_t)N * 8 * 2;
    unsigned short* h1  = (unsigned short*)p; p += (size_t)N * 32 * 2;
    unsigned short* h2  = (unsigned short*)p; p += (size_t)N * 64 * 2;
    unsigned short* h3  = (unsigned short*)p; p += (size_t)N * 124 * 2;
    float* gbuf = (float*)p; p += 64 * 124 * 4;
    float* cntF = (float*)p; p += 256;
    int*   cntI = (int*)p;   p += ((size_t)N * 4 + 15) & ~15ULL;
    int*   off  = (int*)p;   p += ((size_t)N * 4 + 15) & ~15ULL;
    int*   bsum = (int*)p;   p += SCAN_B * 4;
    int4*  rec  = (int4*)p;  p += (size_t)E * 16;
    unsigned short* WT1 = (unsigned short*)p; p += (size_t)32  * KP1 * 2;
    unsigned short* WT2 = (unsigned short*)p; p += (size_t)64  * KP2 * 2;
    unsigned short* WT3 = (unsigned short*)p; p += (size_t)128 * KP3 * 2;
    unsigned short* accB = (unsigned short*)p;
    size_t used = (size_t)(p - (char*)d_ws);
    size_t avail = (ws_size > used) ? (ws_size - used) : 0;

    // zero: gbuf + cntF + cntI (contiguous)
    hipMemsetAsync(gbuf, 0, 64 * 124 * 4 + 256 + (((size_t)N * 4 + 15) & ~15ULL), stream);

    // CSR build
    int nb_scan = (N + SCAN_B - 1) / SCAN_B;
    csr_count_kernel<<<(E + 255) / 256, 256, 0, stream>>>(dstp, cntI, E);
    scan1_kernel<<<nb_scan, SCAN_B, 0, stream>>>(cntI, off, bsum, N);
    scan2_kernel<<<1, SCAN_B, 0, stream>>>(bsum, nb_scan);
    scan3_kernel<<<nb_scan, SCAN_B, 0, stream>>>(off, bsum, N);
    csr_fill_kernel<<<(E + 255) / 256, 256, 0, stream>>>(srcp, dstp, pseudo, off, rec, E);

    // conversions / weight prep
    to_bf16_kernel<<<(N * 8 + 255) / 256, 256, 0, stream>>>(x, xb, N * 8);
    build_wt_kernel<KP1, 8,  32,  32 ><<<(32  * KP1 + 255) / 256, 256, 0, stream>>>(W1, r1, WT1);
    build_wt_kernel<KP2, 32, 64,  64 ><<<(64  * KP2 + 255) / 256, 256, 0, stream>>>(W2, r2, WT2);
    build_wt_kernel<KP3, 64, 124, 128><<<(128 * KP3 + 255) / 256, 256, 0, stream>>>(W3, r3, WT3);

    run_layer<8,  32,  32 >(xb, WT1, b1, h1, accB, rec, off, N, avail, stream);
    run_layer<32, 64,  64 >(h1, WT2, b2, h2, accB, rec, off, N, avail, stream);
    run_layer<64, 124, 128>(h2, WT3, b3, h3, accB, rec, off, N, avail, stream);

    graph_reduce_kernel<<<(N + GS_CH - 1) / GS_CH, 128, 0, stream>>>(h3, batch, gbuf, N);
    batch_count_kernel<<<(N + 255) / 256, 256, 0, stream>>>(batch, cntF, N);
    head_kernel<<<64, 64, 0, stream>>>(gbuf, cntF, fcw, fcb, (float*)d_out);
}